// Round 2
// baseline (475.036 us; speedup 1.0000x reference)
//
#include <hip/hip_runtime.h>
#include <hip/hip_bf16.h>

#define HEADS   16
#define GROUPS  4
#define C_IN    1024
#define C_OUT   1024
#define BATCH   4
#define SEQ     1024
#define DHEAD   64      // C_OUT / HEADS
#define DPG     256     // C_IN / GROUPS
#define MROWS   (BATCH * SEQ)   // 4096

// ---------------------------------------------------------------------------
// Grouped projection: out[b,h,s,d] = sum_k x[b,s, g*256+k] * w[g,k,o] + bias
// One (64-row x 64-col) tile per block, 256 threads, 4x4 micro-tile/thread.
// LDS holds A k-major (transposed) and B row-major so the inner loop is
// 2x ds_read_b128 + 16x v_fma_f32 with broadcast / 2-way (free) bank access.
// ---------------------------------------------------------------------------
__launch_bounds__(256, 4)
__global__ void proj_kernel(const float* __restrict__ x,    // [B*S, C_IN]
                            const float* __restrict__ w,    // [G, DPG, DPG]
                            const float* __restrict__ bias, // [C_OUT]
                            float* __restrict__ out)        // [B, H, S, DHEAD]
{
    const int tid = threadIdx.x;
    const int tx  = tid & 15;
    const int ty  = tid >> 4;
    const int m0  = blockIdx.x * 64;   // row tile (over B*S)
    const int o0  = blockIdx.y * 64;   // col tile within group
    const int g   = blockIdx.z;        // group

    __shared__ float At[32][68];   // k-major: At[kk][r] = x[m0+r][k0+kk]
    __shared__ float Bs[32][68];   // row-major: Bs[kk][o]

    float acc[4][4] = {};

    const float* xg = x + (size_t)m0 * C_IN + g * DPG;
    const float* wg = w + (size_t)g * DPG * DPG + o0;

    for (int k0 = 0; k0 < DPG; k0 += 32) {
        // ---- stage A tile: 64 rows x 32 k  (transpose into LDS)
        {
            const int r  = tid >> 3;   // 0..31
            const int c4 = tid & 7;    // 0..7  (k/4)
#pragma unroll
            for (int p = 0; p < 2; ++p) {
                const int rr = p * 32 + r;
                const float4 v = *reinterpret_cast<const float4*>(
                    xg + (size_t)rr * C_IN + k0 + c4 * 4);
                At[c4 * 4 + 0][rr] = v.x;
                At[c4 * 4 + 1][rr] = v.y;
                At[c4 * 4 + 2][rr] = v.z;
                At[c4 * 4 + 3][rr] = v.w;
            }
        }
        // ---- stage B tile: 32 k x 64 o
        {
            const int kk = tid >> 4;   // 0..15
            const int o4 = tid & 15;   // 0..15
#pragma unroll
            for (int p = 0; p < 2; ++p) {
                const int kr = p * 16 + kk;
                const float4 v = *reinterpret_cast<const float4*>(
                    wg + (size_t)(k0 + kr) * DPG + o4 * 4);
                *reinterpret_cast<float4*>(&Bs[kr][o4 * 4]) = v;
            }
        }
        __syncthreads();

#pragma unroll
        for (int kk = 0; kk < 32; ++kk) {
            const float4 a = *reinterpret_cast<const float4*>(&At[kk][ty * 4]);
            const float4 b = *reinterpret_cast<const float4*>(&Bs[kk][tx * 4]);
            acc[0][0] = fmaf(a.x, b.x, acc[0][0]);
            acc[0][1] = fmaf(a.x, b.y, acc[0][1]);
            acc[0][2] = fmaf(a.x, b.z, acc[0][2]);
            acc[0][3] = fmaf(a.x, b.w, acc[0][3]);
            acc[1][0] = fmaf(a.y, b.x, acc[1][0]);
            acc[1][1] = fmaf(a.y, b.y, acc[1][1]);
            acc[1][2] = fmaf(a.y, b.z, acc[1][2]);
            acc[1][3] = fmaf(a.y, b.w, acc[1][3]);
            acc[2][0] = fmaf(a.z, b.x, acc[2][0]);
            acc[2][1] = fmaf(a.z, b.y, acc[2][1]);
            acc[2][2] = fmaf(a.z, b.z, acc[2][2]);
            acc[2][3] = fmaf(a.z, b.w, acc[2][3]);
            acc[3][0] = fmaf(a.w, b.x, acc[3][0]);
            acc[3][1] = fmaf(a.w, b.y, acc[3][1]);
            acc[3][2] = fmaf(a.w, b.z, acc[3][2]);
            acc[3][3] = fmaf(a.w, b.w, acc[3][3]);
        }
        __syncthreads();
    }

    // ---- epilogue: + bias, scatter into [B, H, S, DHEAD]
    const int cbase = g * DPG + o0 + tx * 4;   // global output channel (j=0)
    const int h     = cbase >> 6;
    const int dd    = cbase & 63;
    const float4 bv = *reinterpret_cast<const float4*>(bias + cbase);
#pragma unroll
    for (int i = 0; i < 4; ++i) {
        const int m  = m0 + ty * 4 + i;
        const int bB = m >> 10;        // / SEQ
        const int s  = m & 1023;
        float4 o;
        o.x = acc[i][0] + bv.x;
        o.y = acc[i][1] + bv.y;
        o.z = acc[i][2] + bv.z;
        o.w = acc[i][3] + bv.w;
        *reinterpret_cast<float4*>(
            out + ((((size_t)bB * HEADS + h) * SEQ + s) * DHEAD + dd)) = o;
    }
}

// ---------------------------------------------------------------------------
// Flash attention with "restricted softmax":
//   smax = max(rowmax, 0); denom = sum(exp(s - smax)) + exp(-smax)
// The margin term is exactly a phantom score of 0 => init m=0, l=1, acc=0
// and run the standard online-softmax recurrence.
// One block = 64 query rows for one (b,h); 16 K/V tiles of 64.
// ---------------------------------------------------------------------------
__launch_bounds__(256, 2)
__global__ void attn_kernel(const float* __restrict__ qb,  // [B,H,S,64]
                            const float* __restrict__ kb,
                            const float* __restrict__ vb,
                            float* __restrict__ out)       // [B,S,C_OUT]
{
    const int tid = threadIdx.x;
    const int tx  = tid & 15;
    const int ty  = tid >> 4;
    const int q0  = blockIdx.x * 64;
    const int bh  = blockIdx.y;          // b*HEADS + h
    const int b   = bh >> 4;
    const int h   = bh & 15;

    __shared__ float Qt[64][68];   // k-major:  Qt[kdim][qrow]
    __shared__ float Kt[64][68];   // k-major:  Kt[kdim][krow]
    __shared__ float Vs[64][68];   // row-major Vs[krow][d]
    __shared__ float Ps[64][68];   // row-major P tile

    const float* qp = qb + (size_t)bh * SEQ * DHEAD;
    const float* kp = kb + (size_t)bh * SEQ * DHEAD;
    const float* vp = vb + (size_t)bh * SEQ * DHEAD;

    // ---- load Q tile (transposed) once
    {
        const int r  = tid >> 4;   // 0..15
        const int c4 = tid & 15;   // 0..15
#pragma unroll
        for (int p = 0; p < 4; ++p) {
            const int rr = p * 16 + r;
            const float4 v = *reinterpret_cast<const float4*>(
                qp + (size_t)(q0 + rr) * DHEAD + c4 * 4);
            Qt[c4 * 4 + 0][rr] = v.x;
            Qt[c4 * 4 + 1][rr] = v.y;
            Qt[c4 * 4 + 2][rr] = v.z;
            Qt[c4 * 4 + 3][rr] = v.w;
        }
    }

    float m_i[4] = {0.f, 0.f, 0.f, 0.f};   // running max, clamped at 0 (margin)
    float l_i[4] = {1.f, 1.f, 1.f, 1.f};   // phantom exp(0 - 0) term
    float acc[4][4] = {};

    const float scale = 0.125f;            // 1/sqrt(64)

    for (int kt = 0; kt < 16; ++kt) {
        const int k0 = kt * 64;
        // ---- stage K (transposed) and V (row-major)
        {
            const int r  = tid >> 4;
            const int c4 = tid & 15;
#pragma unroll
            for (int p = 0; p < 4; ++p) {
                const int rr = p * 16 + r;
                const float4 kv = *reinterpret_cast<const float4*>(
                    kp + (size_t)(k0 + rr) * DHEAD + c4 * 4);
                Kt[c4 * 4 + 0][rr] = kv.x;
                Kt[c4 * 4 + 1][rr] = kv.y;
                Kt[c4 * 4 + 2][rr] = kv.z;
                Kt[c4 * 4 + 3][rr] = kv.w;
                const float4 vv = *reinterpret_cast<const float4*>(
                    vp + (size_t)(k0 + rr) * DHEAD + c4 * 4);
                *reinterpret_cast<float4*>(&Vs[rr][c4 * 4]) = vv;
            }
        }
        __syncthreads();

        // ---- S tile = Q K^T (64x64), 4x4 per thread
        float s[4][4] = {};
#pragma unroll 16
        for (int kk = 0; kk < 64; ++kk) {
            const float4 a = *reinterpret_cast<const float4*>(&Qt[kk][ty * 4]);
            const float4 b4 = *reinterpret_cast<const float4*>(&Kt[kk][tx * 4]);
            s[0][0] = fmaf(a.x, b4.x, s[0][0]);
            s[0][1] = fmaf(a.x, b4.y, s[0][1]);
            s[0][2] = fmaf(a.x, b4.z, s[0][2]);
            s[0][3] = fmaf(a.x, b4.w, s[0][3]);
            s[1][0] = fmaf(a.y, b4.x, s[1][0]);
            s[1][1] = fmaf(a.y, b4.y, s[1][1]);
            s[1][2] = fmaf(a.y, b4.z, s[1][2]);
            s[1][3] = fmaf(a.y, b4.w, s[1][3]);
            s[2][0] = fmaf(a.z, b4.x, s[2][0]);
            s[2][1] = fmaf(a.z, b4.y, s[2][1]);
            s[2][2] = fmaf(a.z, b4.z, s[2][2]);
            s[2][3] = fmaf(a.z, b4.w, s[2][3]);
            s[3][0] = fmaf(a.w, b4.x, s[3][0]);
            s[3][1] = fmaf(a.w, b4.y, s[3][1]);
            s[3][2] = fmaf(a.w, b4.z, s[3][2]);
            s[3][3] = fmaf(a.w, b4.w, s[3][3]);
        }

        // ---- online restricted softmax (rows owned by 16 tx-lanes)
#pragma unroll
        for (int i = 0; i < 4; ++i) {
            float rm = fmaxf(fmaxf(s[i][0], s[i][1]), fmaxf(s[i][2], s[i][3]));
            rm *= scale;   // scale>0 so max commutes with scaling
            rm = fmaxf(rm, __shfl_xor(rm, 1));
            rm = fmaxf(rm, __shfl_xor(rm, 2));
            rm = fmaxf(rm, __shfl_xor(rm, 4));
            rm = fmaxf(rm, __shfl_xor(rm, 8));
            const float mn = fmaxf(m_i[i], rm);
            const float sf = __expf(m_i[i] - mn);
            float p0, p1, p2, p3;
            p0 = __expf(fmaf(s[i][0], scale, -mn));
            p1 = __expf(fmaf(s[i][1], scale, -mn));
            p2 = __expf(fmaf(s[i][2], scale, -mn));
            p3 = __expf(fmaf(s[i][3], scale, -mn));
            float rs = p0 + p1 + p2 + p3;
            rs += __shfl_xor(rs, 1);
            rs += __shfl_xor(rs, 2);
            rs += __shfl_xor(rs, 4);
            rs += __shfl_xor(rs, 8);
            l_i[i] = l_i[i] * sf + rs;
            m_i[i] = mn;
            acc[i][0] *= sf;
            acc[i][1] *= sf;
            acc[i][2] *= sf;
            acc[i][3] *= sf;
            float4 pv;
            pv.x = p0; pv.y = p1; pv.z = p2; pv.w = p3;
            *reinterpret_cast<float4*>(&Ps[ty * 4 + i][tx * 4]) = pv;
        }
        __syncthreads();

        // ---- acc += P @ V
#pragma unroll 4
        for (int k4 = 0; k4 < 16; ++k4) {
            float pr[4][4];
#pragma unroll
            for (int i = 0; i < 4; ++i) {
                const float4 p4 = *reinterpret_cast<const float4*>(&Ps[ty * 4 + i][k4 * 4]);
                pr[i][0] = p4.x; pr[i][1] = p4.y; pr[i][2] = p4.z; pr[i][3] = p4.w;
            }
#pragma unroll
            for (int t = 0; t < 4; ++t) {
                const float4 vv = *reinterpret_cast<const float4*>(&Vs[k4 * 4 + t][tx * 4]);
#pragma unroll
                for (int i = 0; i < 4; ++i) {
                    acc[i][0] = fmaf(pr[i][t], vv.x, acc[i][0]);
                    acc[i][1] = fmaf(pr[i][t], vv.y, acc[i][1]);
                    acc[i][2] = fmaf(pr[i][t], vv.z, acc[i][2]);
                    acc[i][3] = fmaf(pr[i][t], vv.w, acc[i][3]);
                }
            }
        }
        __syncthreads();
    }

    // ---- epilogue: out[b, s, h*64 + d] = acc / l
#pragma unroll
    for (int i = 0; i < 4; ++i) {
        const int srow = q0 + ty * 4 + i;
        const float inv = 1.0f / l_i[i];
        float4 o;
        o.x = acc[i][0] * inv;
        o.y = acc[i][1] * inv;
        o.z = acc[i][2] * inv;
        o.w = acc[i][3] * inv;
        *reinterpret_cast<float4*>(
            out + (((size_t)b * SEQ + srow) * C_OUT + h * DHEAD + tx * 4)) = o;
    }
}

extern "C" void kernel_launch(void* const* d_in, const int* in_sizes, int n_in,
                              void* d_out, int out_size, void* d_ws, size_t ws_size,
                              hipStream_t stream) {
    const float* query = (const float*)d_in[0];
    const float* key   = (const float*)d_in[1];
    const float* value = (const float*)d_in[2];
    const float* wq    = (const float*)d_in[3];
    const float* bq    = (const float*)d_in[4];
    const float* wk    = (const float*)d_in[5];
    const float* bk    = (const float*)d_in[6];
    const float* wv    = (const float*)d_in[7];
    const float* bv    = (const float*)d_in[8];

    const size_t per = (size_t)BATCH * HEADS * SEQ * DHEAD;  // 4,194,304 floats
    float* qbuf = (float*)d_ws;
    float* kbuf = qbuf + per;
    float* vbuf = kbuf + per;

    dim3 blk(256);
    dim3 pg(MROWS / 64, DPG / 64, GROUPS);   // (64, 4, 4)
    proj_kernel<<<pg, blk, 0, stream>>>(query, wq, bq, qbuf);
    proj_kernel<<<pg, blk, 0, stream>>>(key,   wk, bk, kbuf);
    proj_kernel<<<pg, blk, 0, stream>>>(value, wv, bv, vbuf);

    dim3 ag(SEQ / 64, BATCH * HEADS);        // (16, 64)
    attn_kernel<<<ag, blk, 0, stream>>>(qbuf, kbuf, vbuf, (float*)d_out);
}

// Round 4
// 263.133 us; speedup vs baseline: 1.8053x; 1.8053x over previous
//
#include <hip/hip_runtime.h>
#include <hip/hip_bf16.h>

#define HEADS   16
#define GROUPS  4
#define C_IN    1024
#define C_OUT   1024
#define BATCH   4
#define SEQ     1024
#define DHEAD   64
#define DPG     256
#define MROWS   (BATCH * SEQ)   // 4096
#define NBH     (BATCH * HEADS) // 64

typedef short  bhalf8  __attribute__((ext_vector_type(8)));
typedef short  short4v __attribute__((ext_vector_type(4)));
typedef float  f32x4   __attribute__((ext_vector_type(4)));

#define MFMA16 __builtin_amdgcn_mfma_f32_16x16x32_bf16

// round-to-nearest-even f32 -> bf16 bits
__device__ __forceinline__ unsigned short f2bf(float x) {
    unsigned int u = __float_as_uint(x);
    u = u + 0x7FFFu + ((u >> 16) & 1u);
    return (unsigned short)(u >> 16);
}
__device__ __forceinline__ float bf2f(unsigned short s) {
    return __uint_as_float(((unsigned int)s) << 16);
}

// ---------------------------------------------------------------------------
// Grouped projection (f32 VALU core, unchanged from the passing Round-2
// kernel). Epilogue emits SPLIT bf16 (hi + residual-lo) operands for 3-term
// split MFMA in the attention kernel.
//   MODE 0: out[bh][s][64]   (q, k)
//   MODE 1: out[bh][d][s]    (V pre-transposed -> attn staging is row-major)
// ---------------------------------------------------------------------------
template<int MODE>
__launch_bounds__(256, 4)
__global__ void proj_kernel(const float* __restrict__ x,    // [B*S, C_IN]
                            const float* __restrict__ w,    // [G, DPG, DPG]
                            const float* __restrict__ bias, // [C_OUT]
                            unsigned short* __restrict__ outh,
                            unsigned short* __restrict__ outl)
{
    const int tid = threadIdx.x;
    const int tx  = tid & 15;
    const int ty  = tid >> 4;
    const int m0  = blockIdx.x * 64;
    const int o0  = blockIdx.y * 64;
    const int g   = blockIdx.z;

    __shared__ float At[32][68];
    __shared__ float Bs[32][68];

    float acc[4][4] = {};

    const float* xg = x + (size_t)m0 * C_IN + g * DPG;
    const float* wg = w + (size_t)g * DPG * DPG + o0;

    for (int k0 = 0; k0 < DPG; k0 += 32) {
        {
            const int r  = tid >> 3;
            const int c4 = tid & 7;
#pragma unroll
            for (int p = 0; p < 2; ++p) {
                const int rr = p * 32 + r;
                const float4 v = *reinterpret_cast<const float4*>(
                    xg + (size_t)rr * C_IN + k0 + c4 * 4);
                At[c4 * 4 + 0][rr] = v.x;
                At[c4 * 4 + 1][rr] = v.y;
                At[c4 * 4 + 2][rr] = v.z;
                At[c4 * 4 + 3][rr] = v.w;
            }
        }
        {
            const int kk = tid >> 4;
            const int o4 = tid & 15;
#pragma unroll
            for (int p = 0; p < 2; ++p) {
                const int kr = p * 16 + kk;
                const float4 v = *reinterpret_cast<const float4*>(
                    wg + (size_t)(k0 + kr) * DPG + o4 * 4);
                *reinterpret_cast<float4*>(&Bs[kr][o4 * 4]) = v;
            }
        }
        __syncthreads();

#pragma unroll
        for (int kk = 0; kk < 32; ++kk) {
            const float4 a = *reinterpret_cast<const float4*>(&At[kk][ty * 4]);
            const float4 b = *reinterpret_cast<const float4*>(&Bs[kk][tx * 4]);
            acc[0][0] = fmaf(a.x, b.x, acc[0][0]);
            acc[0][1] = fmaf(a.x, b.y, acc[0][1]);
            acc[0][2] = fmaf(a.x, b.z, acc[0][2]);
            acc[0][3] = fmaf(a.x, b.w, acc[0][3]);
            acc[1][0] = fmaf(a.y, b.x, acc[1][0]);
            acc[1][1] = fmaf(a.y, b.y, acc[1][1]);
            acc[1][2] = fmaf(a.y, b.z, acc[1][2]);
            acc[1][3] = fmaf(a.y, b.w, acc[1][3]);
            acc[2][0] = fmaf(a.z, b.x, acc[2][0]);
            acc[2][1] = fmaf(a.z, b.y, acc[2][1]);
            acc[2][2] = fmaf(a.z, b.z, acc[2][2]);
            acc[2][3] = fmaf(a.z, b.w, acc[2][3]);
            acc[3][0] = fmaf(a.w, b.x, acc[3][0]);
            acc[3][1] = fmaf(a.w, b.y, acc[3][1]);
            acc[3][2] = fmaf(a.w, b.z, acc[3][2]);
            acc[3][3] = fmaf(a.w, b.w, acc[3][3]);
        }
        __syncthreads();
    }

    const int cbase = g * DPG + o0 + tx * 4;   // global channel
    const int hh    = cbase >> 6;              // head
    const int db    = cbase & 63;              // d within head (mult of 4)
    const float4 bv = *reinterpret_cast<const float4*>(bias + cbase);
    const int bB = m0 >> 10;                   // batch (const over tile)
    const int s0 = (m0 & 1023) + ty * 4;
    const size_t bhbase = ((size_t)bB * HEADS + hh) * (SEQ * DHEAD);

    if (MODE == 0) {
#pragma unroll
        for (int i = 0; i < 4; ++i) {
            float v0 = acc[i][0] + bv.x, v1 = acc[i][1] + bv.y;
            float v2 = acc[i][2] + bv.z, v3 = acc[i][3] + bv.w;
            ushort4 hv, lv;
            hv.x = f2bf(v0); lv.x = f2bf(v0 - bf2f(hv.x));
            hv.y = f2bf(v1); lv.y = f2bf(v1 - bf2f(hv.y));
            hv.z = f2bf(v2); lv.z = f2bf(v2 - bf2f(hv.z));
            hv.w = f2bf(v3); lv.w = f2bf(v3 - bf2f(hv.w));
            const size_t o = bhbase + (size_t)(s0 + i) * DHEAD + db;
            *reinterpret_cast<ushort4*>(outh + o) = hv;
            *reinterpret_cast<ushort4*>(outl + o) = lv;
        }
    } else {
        const float bj[4] = {bv.x, bv.y, bv.z, bv.w};
#pragma unroll
        for (int j = 0; j < 4; ++j) {
            ushort4 hv, lv;
            float v0 = acc[0][j] + bj[j], v1 = acc[1][j] + bj[j];
            float v2 = acc[2][j] + bj[j], v3 = acc[3][j] + bj[j];
            hv.x = f2bf(v0); lv.x = f2bf(v0 - bf2f(hv.x));
            hv.y = f2bf(v1); lv.y = f2bf(v1 - bf2f(hv.y));
            hv.z = f2bf(v2); lv.z = f2bf(v2 - bf2f(hv.z));
            hv.w = f2bf(v3); lv.w = f2bf(v3 - bf2f(hv.w));
            const size_t o = bhbase + (size_t)(db + j) * SEQ + s0;
            *reinterpret_cast<ushort4*>(outh + o) = hv;
            *reinterpret_cast<ushort4*>(outl + o) = lv;
        }
    }
}

// ---------------------------------------------------------------------------
// Split-bf16 MFMA flash attention (restricted softmax = phantom score 0).
// Block: 256 thr = 4 waves, 128 q-rows (32/wave), one (b,h). 16 K-tiles of 64.
// Swapped QK^T (mfma(K,Q) -> S^T) puts softmax state at q = lane&15; the PV
// reduction axis is kappa-permuted (k = 32kt + 16(j>>2) + 4h + (j&3)) so PV
// A-frags are the lane's own P values -- no cross-lane P movement. K and
// pre-transposed V staged in LDS with XOR swizzle (byte ^= (row&7)<<4).
// ---------------------------------------------------------------------------
__launch_bounds__(256, 2)
__global__ void attn_mfma(const unsigned short* __restrict__ qh,
                          const unsigned short* __restrict__ ql,
                          const unsigned short* __restrict__ kh,
                          const unsigned short* __restrict__ kl,
                          const unsigned short* __restrict__ vth,
                          const unsigned short* __restrict__ vtl,
                          float* __restrict__ out)   // [B,S,C_OUT]
{
    const int tid  = threadIdx.x;
    const int wave = tid >> 6;
    const int lane = tid & 63;
    const int h    = lane >> 4;   // 16-lane group
    const int ln   = lane & 15;
    const int bh   = blockIdx.y;
    const int q0   = blockIdx.x * 128 + wave * 32;

    const size_t bhbase = (size_t)bh * (SEQ * DHEAD);
    const unsigned short* qhp = qh + bhbase;
    const unsigned short* qlp = ql + bhbase;
    const unsigned short* khp = kh + bhbase;
    const unsigned short* klp = kl + bhbase;
    const unsigned short* vhp = vth + bhbase;
    const unsigned short* vlp = vtl + bhbase;

    __shared__ uint4 smem4[2048];          // 32 KB: KH | KL | VH | VL (8KB each)
    char* sb = (char*)smem4;

    // ---- hoist Q fragments (B-operand: lane ln = q-col, elems d = 32*dt+8h+j)
    bhalf8 Qf[2][2][2];                    // [nt][dt][hi/lo]
#pragma unroll
    for (int nt = 0; nt < 2; ++nt)
#pragma unroll
        for (int dt = 0; dt < 2; ++dt) {
            const size_t o = (size_t)(q0 + 16 * nt + ln) * DHEAD + dt * 32 + 8 * h;
            Qf[nt][dt][0] = *reinterpret_cast<const bhalf8*>(qhp + o);
            Qf[nt][dt][1] = *reinterpret_cast<const bhalf8*>(qlp + o);
        }

    f32x4 accO[2][4];
#pragma unroll
    for (int a = 0; a < 2; ++a)
#pragma unroll
        for (int b = 0; b < 4; ++b) accO[a][b] = (f32x4){0.f, 0.f, 0.f, 0.f};
    float m_i[2] = {0.f, 0.f};             // margin: phantom score 0
    float l_i[2] = {1.f, 1.f};
    const float scale = 0.125f;

    for (int kt16 = 0; kt16 < 16; ++kt16) {
        const int k0 = kt16 * 64;
        // ---- stage K (hi,lo) rows [64][64] and VT (hi,lo) rows [64 d][64 k]
        {
            const int r = tid >> 2, c = tid & 3;
            const int swz = (r & 7) << 4;
            const size_t gK = (size_t)(k0 + r) * DHEAD + c * 16;
            const size_t gV = (size_t)r * SEQ + k0 + c * 16;
            const int d0 = r * 128 + ((c * 32) ^ swz);
            const int d1 = r * 128 + ((c * 32 + 16) ^ swz);
            uint4 t;
            t = *reinterpret_cast<const uint4*>(khp + gK);
            *reinterpret_cast<uint4*>(sb + d0) = t;
            t = *reinterpret_cast<const uint4*>(khp + gK + 8);
            *reinterpret_cast<uint4*>(sb + d1) = t;
            t = *reinterpret_cast<const uint4*>(klp + gK);
            *reinterpret_cast<uint4*>(sb + 8192 + d0) = t;
            t = *reinterpret_cast<const uint4*>(klp + gK + 8);
            *reinterpret_cast<uint4*>(sb + 8192 + d1) = t;
            t = *reinterpret_cast<const uint4*>(vhp + gV);
            *reinterpret_cast<uint4*>(sb + 16384 + d0) = t;
            t = *reinterpret_cast<const uint4*>(vhp + gV + 8);
            *reinterpret_cast<uint4*>(sb + 16384 + d1) = t;
            t = *reinterpret_cast<const uint4*>(vlp + gV);
            *reinterpret_cast<uint4*>(sb + 24576 + d0) = t;
            t = *reinterpret_cast<const uint4*>(vlp + gV + 8);
            *reinterpret_cast<uint4*>(sb + 24576 + d1) = t;
        }
        __syncthreads();

        // ---- S^T = K · Q^T  (3-term split), acc: [nt][mt] rows k=16mt+4h+r
        f32x4 s_[2][4];
#pragma unroll
        for (int a = 0; a < 2; ++a)
#pragma unroll
            for (int b = 0; b < 4; ++b) s_[a][b] = (f32x4){0.f, 0.f, 0.f, 0.f};
#pragma unroll
        for (int mt = 0; mt < 4; ++mt) {
            const int rr = 16 * mt + ln;
            const int sw = (rr & 7) << 4;
            const bhalf8 Ah0 = *reinterpret_cast<const bhalf8*>(sb + rr * 128 + ((16 * h) ^ sw));
            const bhalf8 Ah1 = *reinterpret_cast<const bhalf8*>(sb + rr * 128 + ((64 + 16 * h) ^ sw));
            const bhalf8 Al0 = *reinterpret_cast<const bhalf8*>(sb + 8192 + rr * 128 + ((16 * h) ^ sw));
            const bhalf8 Al1 = *reinterpret_cast<const bhalf8*>(sb + 8192 + rr * 128 + ((64 + 16 * h) ^ sw));
#pragma unroll
            for (int nt = 0; nt < 2; ++nt) {
                s_[nt][mt] = MFMA16(Ah0, Qf[nt][0][0], s_[nt][mt], 0, 0, 0);
                s_[nt][mt] = MFMA16(Ah1, Qf[nt][1][0], s_[nt][mt], 0, 0, 0);
                s_[nt][mt] = MFMA16(Ah0, Qf[nt][0][1], s_[nt][mt], 0, 0, 0);
                s_[nt][mt] = MFMA16(Ah1, Qf[nt][1][1], s_[nt][mt], 0, 0, 0);
                s_[nt][mt] = MFMA16(Al0, Qf[nt][0][0], s_[nt][mt], 0, 0, 0);
                s_[nt][mt] = MFMA16(Al1, Qf[nt][1][0], s_[nt][mt], 0, 0, 0);
            }
        }

        // ---- online restricted softmax; P values stay in-lane
        float Pv[2][4][4];
        bhalf8 Pfh[2][2], Pfl[2][2];       // [nt][kt]
#pragma unroll
        for (int nt = 0; nt < 2; ++nt) {
            float mloc = -1e30f;
#pragma unroll
            for (int mt = 0; mt < 4; ++mt)
#pragma unroll
                for (int r = 0; r < 4; ++r) {
                    const float v = s_[nt][mt][r] * scale;
                    Pv[nt][mt][r] = v;
                    mloc = fmaxf(mloc, v);
                }
            mloc = fmaxf(mloc, __shfl_xor(mloc, 16));
            mloc = fmaxf(mloc, __shfl_xor(mloc, 32));
            const float mn = fmaxf(m_i[nt], mloc);
            const float sf = __expf(m_i[nt] - mn);
            m_i[nt] = mn;
            float rs = 0.f;
#pragma unroll
            for (int mt = 0; mt < 4; ++mt)
#pragma unroll
                for (int r = 0; r < 4; ++r) {
                    const float p = __expf(Pv[nt][mt][r] - mn);
                    Pv[nt][mt][r] = p;
                    rs += p;
                }
            rs += __shfl_xor(rs, 16);
            rs += __shfl_xor(rs, 32);
            l_i[nt] = l_i[nt] * sf + rs;
            // rescale O rows q = 16*nt + 4h + r  (sf lives at lane ln = 4h+r)
#pragma unroll
            for (int r = 0; r < 4; ++r) {
                const float sf_b = __shfl(sf, 20 * h + r);
#pragma unroll
                for (int ntd = 0; ntd < 4; ++ntd) accO[nt][ntd][r] *= sf_b;
            }
            // split P into bf16 hi/lo A-frags (kappa order: elem j of kt is
            // P[2kt + (j>>2)][j&3]  <->  k = 32kt + 16(j>>2) + 4h + (j&3))
#pragma unroll
            for (int kt = 0; kt < 2; ++kt) {
                bhalf8 fh, fl;
#pragma unroll
                for (int j = 0; j < 8; ++j) {
                    const float p = Pv[nt][2 * kt + (j >> 2)][j & 3];
                    const unsigned short hi = f2bf(p);
                    fh[j] = (short)hi;
                    fl[j] = (short)f2bf(p - bf2f(hi));
                }
                Pfh[nt][kt] = fh;
                Pfl[nt][kt] = fl;
            }
        }

        // ---- O += P · V  (3-term split), B-frags from VT with matching kappa
#pragma unroll
        for (int kt = 0; kt < 2; ++kt) {
#pragma unroll
            for (int ntd = 0; ntd < 4; ++ntd) {
                const int rr = 16 * ntd + ln;
                const int sw = (rr & 7) << 4;
                const int c0 = (64 * kt + 8 * h) ^ sw;
                const int c1 = (64 * kt + 32 + 8 * h) ^ sw;
                union { short4v q[2]; bhalf8 v; } ubh, ubl;
                ubh.q[0] = *reinterpret_cast<const short4v*>(sb + 16384 + rr * 128 + c0);
                ubh.q[1] = *reinterpret_cast<const short4v*>(sb + 16384 + rr * 128 + c1);
                ubl.q[0] = *reinterpret_cast<const short4v*>(sb + 24576 + rr * 128 + c0);
                ubl.q[1] = *reinterpret_cast<const short4v*>(sb + 24576 + rr * 128 + c1);
                const bhalf8 Bh = ubh.v;
                const bhalf8 Bl = ubl.v;
#pragma unroll
                for (int nt = 0; nt < 2; ++nt) {
                    accO[nt][ntd] = MFMA16(Pfh[nt][kt], Bh, accO[nt][ntd], 0, 0, 0);
                    accO[nt][ntd] = MFMA16(Pfh[nt][kt], Bl, accO[nt][ntd], 0, 0, 0);
                    accO[nt][ntd] = MFMA16(Pfl[nt][kt], Bh, accO[nt][ntd], 0, 0, 0);
                }
            }
        }
        __syncthreads();
    }

    // ---- epilogue: divide by l (broadcast from lane ln = 4h+r), scatter
    const int bB = bh >> 4;
    const int hd = bh & 15;
#pragma unroll
    for (int nt = 0; nt < 2; ++nt) {
        float linv[4];
#pragma unroll
        for (int r = 0; r < 4; ++r) linv[r] = 1.0f / __shfl(l_i[nt], 20 * h + r);
#pragma unroll
        for (int r = 0; r < 4; ++r) {
            const int q = q0 + 16 * nt + 4 * h + r;
            float* orow = out + ((size_t)bB * SEQ + q) * C_OUT + hd * DHEAD + ln;
#pragma unroll
            for (int ntd = 0; ntd < 4; ++ntd)
                orow[16 * ntd] = accO[nt][ntd][r] * linv[r];
        }
    }
}

extern "C" void kernel_launch(void* const* d_in, const int* in_sizes, int n_in,
                              void* d_out, int out_size, void* d_ws, size_t ws_size,
                              hipStream_t stream) {
    const float* query = (const float*)d_in[0];
    const float* key   = (const float*)d_in[1];
    const float* value = (const float*)d_in[2];
    const float* wq    = (const float*)d_in[3];
    const float* bq    = (const float*)d_in[4];
    const float* wk    = (const float*)d_in[5];
    const float* bk    = (const float*)d_in[6];
    const float* wv    = (const float*)d_in[7];
    const float* bv    = (const float*)d_in[8];

    const size_t N = (size_t)NBH * SEQ * DHEAD;      // 4,194,304 elems
    unsigned short* qhb = (unsigned short*)d_ws;
    unsigned short* qlb = qhb + N;
    unsigned short* khb = qhb + 2 * N;
    unsigned short* klb = qhb + 3 * N;
    unsigned short* vhb = qhb + 4 * N;
    unsigned short* vlb = qhb + 5 * N;               // 48 MB total

    dim3 blk(256);
    dim3 pg(MROWS / 64, DPG / 64, GROUPS);           // (64, 4, 4)
    proj_kernel<0><<<pg, blk, 0, stream>>>(query, wq, bq, qhb, qlb);
    proj_kernel<0><<<pg, blk, 0, stream>>>(key,   wk, bk, khb, klb);
    proj_kernel<1><<<pg, blk, 0, stream>>>(value, wv, bv, vhb, vlb);

    dim3 ag(SEQ / 128, NBH);                         // (8, 64)
    attn_mfma<<<ag, blk, 0, stream>>>(qhb, qlb, khb, klb, vhb, vlb, (float*)d_out);
}

// Round 5
// 217.544 us; speedup vs baseline: 2.1836x; 1.2096x over previous
//
#include <hip/hip_runtime.h>
#include <hip/hip_bf16.h>

#define HEADS   16
#define GROUPS  4
#define C_IN    1024
#define C_OUT   1024
#define BATCH   4
#define SEQ     1024
#define DHEAD   64
#define DPG     256
#define MROWS   (BATCH * SEQ)   // 4096
#define NBH     (BATCH * HEADS) // 64

typedef short  bhalf8  __attribute__((ext_vector_type(8)));
typedef short  short4v __attribute__((ext_vector_type(4)));
typedef float  f32x4   __attribute__((ext_vector_type(4)));
typedef unsigned short ushort8v __attribute__((ext_vector_type(8)));

#define MFMA16 __builtin_amdgcn_mfma_f32_16x16x32_bf16

// round-to-nearest-even f32 -> bf16 bits
__device__ __forceinline__ unsigned short f2bf(float x) {
    unsigned int u = __float_as_uint(x);
    u = u + 0x7FFFu + ((u >> 16) & 1u);
    return (unsigned short)(u >> 16);
}
__device__ __forceinline__ float bf2f(unsigned short s) {
    return __uint_as_float(((unsigned int)s) << 16);
}

// ---------------------------------------------------------------------------
// Weight transpose+split setup: w[g][k][o] f32  ->  wt{h,l}[g][o][k] bf16.
// Tiny (1 MB in), runs once per weight. grid (4,4,4) = (k-tile, o-tile, g).
// ---------------------------------------------------------------------------
__global__ void wsplit(const float* __restrict__ w,
                       unsigned short* __restrict__ wth,
                       unsigned short* __restrict__ wtl)
{
    const int tid = threadIdx.x;
    const int kt = blockIdx.x, ot = blockIdx.y, g = blockIdx.z;
    __shared__ float Ls[64][68];
    const float* wg = w + (size_t)g * DPG * DPG;
#pragma unroll
    for (int p = 0; p < 4; ++p) {
        const int kk = 16 * p + (tid >> 4);
        const int oo = 4 * (tid & 15);
        const float4 v = *reinterpret_cast<const float4*>(
            wg + (size_t)(kt * 64 + kk) * DPG + ot * 64 + oo);
        Ls[kk][oo + 0] = v.x; Ls[kk][oo + 1] = v.y;
        Ls[kk][oo + 2] = v.z; Ls[kk][oo + 3] = v.w;
    }
    __syncthreads();
    unsigned short* th = wth + (size_t)g * DPG * DPG;
    unsigned short* tl = wtl + (size_t)g * DPG * DPG;
#pragma unroll
    for (int p = 0; p < 4; ++p) {
        const int oo = 16 * p + (tid >> 4);
        const int k4 = 4 * (tid & 15);
        ushort4 hv, lv;
        {
            float v0 = Ls[k4 + 0][oo], v1 = Ls[k4 + 1][oo];
            float v2 = Ls[k4 + 2][oo], v3 = Ls[k4 + 3][oo];
            hv.x = f2bf(v0); lv.x = f2bf(v0 - bf2f(hv.x));
            hv.y = f2bf(v1); lv.y = f2bf(v1 - bf2f(hv.y));
            hv.z = f2bf(v2); lv.z = f2bf(v2 - bf2f(hv.z));
            hv.w = f2bf(v3); lv.w = f2bf(v3 - bf2f(hv.w));
        }
        const size_t o = (size_t)(ot * 64 + oo) * DPG + kt * 64 + k4;
        *reinterpret_cast<ushort4*>(th + o) = hv;
        *reinterpret_cast<ushort4*>(tl + o) = lv;
    }
}

// ---------------------------------------------------------------------------
// Split-bf16 MFMA grouped projection.  out[m][o] = sum_k x[m][k] w[k][o] + b.
// Tile 64m x 128o, BK=64, 4 waves (2x2 quadrants of 32x64), 3-term split
// (Ah*Bh + Al*Bh + Ah*Bl).  A (x) is split hi/lo during staging; B comes
// pre-split+transposed from wsplit.  LDS XOR swizzle ((row&7)<<4) everywhere.
// Epilogue: bias + split + per-wave LDS transpose -> coalesced global stores.
//   MODE 0: out[bh][s][64]   (q, k)       MODE 1: out[bh][d][s]   (V)
// ---------------------------------------------------------------------------
template<int MODE>
__launch_bounds__(256, 2)
__global__ void proj_mfma(const float* __restrict__ x,
                          const unsigned short* __restrict__ wth,
                          const unsigned short* __restrict__ wtl,
                          const float* __restrict__ bias,
                          unsigned short* __restrict__ outh,
                          unsigned short* __restrict__ outl)
{
    const int tid  = threadIdx.x;
    const int wave = tid >> 6;
    const int lane = tid & 63;
    const int h    = lane >> 4;
    const int ln   = lane & 15;
    const int mq   = wave >> 1;          // 0..1  (32-row half)
    const int nq   = wave & 1;           // 0..1  (64-col half)
    const int bx   = blockIdx.x;         // 0..63 m-tile
    const int by   = blockIdx.y;         // 0..1  o-half of group
    const int g    = blockIdx.z;
    const int m0   = bx * 64;

    __shared__ uint4 smem4[3072];        // 48 KB
    char* sp = (char*)smem4;             // Ah@0  Al@8192  Bh@16384  Bl@32768

    f32x4 acc[2][4];
#pragma unroll
    for (int a = 0; a < 2; ++a)
#pragma unroll
        for (int b = 0; b < 4; ++b) acc[a][b] = (f32x4){0.f, 0.f, 0.f, 0.f};

    const float* xg = x + (size_t)m0 * C_IN + g * DPG;
    const unsigned short* wh = wth + ((size_t)g * DPG + by * 128) * DPG;
    const unsigned short* wl = wtl + ((size_t)g * DPG + by * 128) * DPG;

    for (int k0 = 0; k0 < DPG; k0 += 64) {
        __syncthreads();                 // prev-iter reads done before restage
        // ---- stage A: 64 rows x 64 k f32 -> split bf16 hi/lo
        {
            const int rb = tid >> 4;     // 0..15
            const int c  = tid & 15;     // k/4
#pragma unroll
            for (int p = 0; p < 4; ++p) {
                const int rr = 16 * p + rb;
                const float4 v = *reinterpret_cast<const float4*>(
                    xg + (size_t)rr * C_IN + k0 + 4 * c);
                ushort4 hv, lv;
                hv.x = f2bf(v.x); lv.x = f2bf(v.x - bf2f(hv.x));
                hv.y = f2bf(v.y); lv.y = f2bf(v.y - bf2f(hv.y));
                hv.z = f2bf(v.z); lv.z = f2bf(v.z - bf2f(hv.z));
                hv.w = f2bf(v.w); lv.w = f2bf(v.w - bf2f(hv.w));
                const int off = (8 * c) ^ ((rr & 7) << 4);
                *reinterpret_cast<ushort4*>(sp + rr * 128 + off) = hv;
                *reinterpret_cast<ushort4*>(sp + 8192 + rr * 128 + off) = lv;
            }
        }
        // ---- stage B: 128 o-rows x 64 k bf16 (pre-split)
        {
            const int rb = tid >> 3;     // 0..31
            const int c  = tid & 7;      // k/8
#pragma unroll
            for (int p = 0; p < 4; ++p) {
                const int rr = 32 * p + rb;
                const int off = (16 * c) ^ ((rr & 7) << 4);
                const size_t gofs = (size_t)rr * DPG + k0 + 8 * c;
                *reinterpret_cast<ushort8v*>(sp + 16384 + rr * 128 + off) =
                    *reinterpret_cast<const ushort8v*>(wh + gofs);
                *reinterpret_cast<ushort8v*>(sp + 32768 + rr * 128 + off) =
                    *reinterpret_cast<const ushort8v*>(wl + gofs);
            }
        }
        __syncthreads();

        // ---- MFMA: 2 kk x (2 mt x 4 nt) x 3 terms
#pragma unroll
        for (int kk = 0; kk < 2; ++kk) {
            bhalf8 ah[2], al[2], bh_[4], bl_[4];
#pragma unroll
            for (int mt = 0; mt < 2; ++mt) {
                const int row = 32 * mq + 16 * mt + ln;
                const int off = (64 * kk + 16 * h) ^ ((row & 7) << 4);
                ah[mt] = *reinterpret_cast<const bhalf8*>(sp + row * 128 + off);
                al[mt] = *reinterpret_cast<const bhalf8*>(sp + 8192 + row * 128 + off);
            }
#pragma unroll
            for (int nt = 0; nt < 4; ++nt) {
                const int row = 64 * nq + 16 * nt + ln;
                const int off = (64 * kk + 16 * h) ^ ((row & 7) << 4);
                bh_[nt] = *reinterpret_cast<const bhalf8*>(sp + 16384 + row * 128 + off);
                bl_[nt] = *reinterpret_cast<const bhalf8*>(sp + 32768 + row * 128 + off);
            }
#pragma unroll
            for (int mt = 0; mt < 2; ++mt)
#pragma unroll
                for (int nt = 0; nt < 4; ++nt) {
                    acc[mt][nt] = MFMA16(ah[mt], bh_[nt], acc[mt][nt], 0, 0, 0);
                    acc[mt][nt] = MFMA16(al[mt], bh_[nt], acc[mt][nt], 0, 0, 0);
                    acc[mt][nt] = MFMA16(ah[mt], bl_[nt], acc[mt][nt], 0, 0, 0);
                }
        }
    }
    __syncthreads();                     // all compute reads done; reuse LDS

    // ---- epilogue
    const int hd = g * 4 + by * 2 + nq;  // head
    const int b  = bx >> 4;
    const size_t bhb = ((size_t)b * HEADS + hd) * (SEQ * DHEAD);
    const int wbase = wave * 8192;       // 4KB hi + 4KB lo per wave
    const int sg0 = (bx & 15) * 64 + 32 * mq;
    float bnt[4];
#pragma unroll
    for (int nt = 0; nt < 4; ++nt)
        bnt[nt] = bias[g * 256 + by * 128 + 64 * nq + 16 * nt + ln];

    if (MODE == 0) {
        // LDS layout per wave: [32 s'][64 o'] ushort, swizzled
#pragma unroll
        for (int mt = 0; mt < 2; ++mt)
#pragma unroll
            for (int nt = 0; nt < 4; ++nt)
#pragma unroll
                for (int r = 0; r < 4; ++r) {
                    const int sl = 16 * mt + 4 * h + r;
                    const float v = acc[mt][nt][r] + bnt[nt];
                    const unsigned short hh = f2bf(v);
                    const unsigned short ll = f2bf(v - bf2f(hh));
                    const int cb = (2 * (16 * nt + ln)) ^ ((sl & 7) << 4);
                    *reinterpret_cast<unsigned short*>(sp + wbase + sl * 128 + cb) = hh;
                    *reinterpret_cast<unsigned short*>(sp + wbase + 4096 + sl * 128 + cb) = ll;
                }
        __syncthreads();
#pragma unroll
        for (int p = 0; p < 4; ++p) {
            const int sl = 8 * p + (lane >> 3);
            const int cb = (16 * (lane & 7)) ^ ((sl & 7) << 4);
            const size_t go = bhb + (size_t)(sg0 + sl) * 64 + 8 * (lane & 7);
            *reinterpret_cast<ushort8v*>(outh + go) =
                *reinterpret_cast<const ushort8v*>(sp + wbase + sl * 128 + cb);
            *reinterpret_cast<ushort8v*>(outl + go) =
                *reinterpret_cast<const ushort8v*>(sp + wbase + 4096 + sl * 128 + cb);
        }
    } else {
        // LDS layout per wave: [64 d'][32 s'] ushort, swizzled (8B granule)
#pragma unroll
        for (int mt = 0; mt < 2; ++mt)
#pragma unroll
            for (int nt = 0; nt < 4; ++nt) {
                const int dl = 16 * nt + ln;
                ushort4 hv, lv;
                {
                    float v0 = acc[mt][nt][0] + bnt[nt];
                    float v1 = acc[mt][nt][1] + bnt[nt];
                    float v2 = acc[mt][nt][2] + bnt[nt];
                    float v3 = acc[mt][nt][3] + bnt[nt];
                    hv.x = f2bf(v0); lv.x = f2bf(v0 - bf2f(hv.x));
                    hv.y = f2bf(v1); lv.y = f2bf(v1 - bf2f(hv.y));
                    hv.z = f2bf(v2); lv.z = f2bf(v2 - bf2f(hv.z));
                    hv.w = f2bf(v3); lv.w = f2bf(v3 - bf2f(hv.w));
                }
                const int off = (32 * mt + 8 * h) ^ ((dl & 7) << 3);
                *reinterpret_cast<ushort4*>(sp + wbase + dl * 64 + off) = hv;
                *reinterpret_cast<ushort4*>(sp + wbase + 4096 + dl * 64 + off) = lv;
            }
        __syncthreads();
#pragma unroll
        for (int p = 0; p < 4; ++p) {
            const int dl  = 16 * p + (lane >> 2);
            const int c16 = 16 * (lane & 3);
            const int o0b = (c16) ^ ((dl & 7) << 3);
            const int o1b = (c16 + 8) ^ ((dl & 7) << 3);
            const size_t go = bhb + (size_t)dl * SEQ + sg0 + 8 * (lane & 3);
            *reinterpret_cast<ushort4*>(outh + go) =
                *reinterpret_cast<const ushort4*>(sp + wbase + dl * 64 + o0b);
            *reinterpret_cast<ushort4*>(outh + go + 4) =
                *reinterpret_cast<const ushort4*>(sp + wbase + dl * 64 + o1b);
            *reinterpret_cast<ushort4*>(outl + go) =
                *reinterpret_cast<const ushort4*>(sp + wbase + 4096 + dl * 64 + o0b);
            *reinterpret_cast<ushort4*>(outl + go + 4) =
                *reinterpret_cast<const ushort4*>(sp + wbase + 4096 + dl * 64 + o1b);
        }
    }
}

// ---------------------------------------------------------------------------
// Split-bf16 MFMA flash attention (UNCHANGED from passing Round-4 kernel).
// ---------------------------------------------------------------------------
__launch_bounds__(256, 2)
__global__ void attn_mfma(const unsigned short* __restrict__ qh,
                          const unsigned short* __restrict__ ql,
                          const unsigned short* __restrict__ kh,
                          const unsigned short* __restrict__ kl,
                          const unsigned short* __restrict__ vth,
                          const unsigned short* __restrict__ vtl,
                          float* __restrict__ out)   // [B,S,C_OUT]
{
    const int tid  = threadIdx.x;
    const int wave = tid >> 6;
    const int lane = tid & 63;
    const int h    = lane >> 4;
    const int ln   = lane & 15;
    const int bh   = blockIdx.y;
    const int q0   = blockIdx.x * 128 + wave * 32;

    const size_t bhbase = (size_t)bh * (SEQ * DHEAD);
    const unsigned short* qhp = qh + bhbase;
    const unsigned short* qlp = ql + bhbase;
    const unsigned short* khp = kh + bhbase;
    const unsigned short* klp = kl + bhbase;
    const unsigned short* vhp = vth + bhbase;
    const unsigned short* vlp = vtl + bhbase;

    __shared__ uint4 smem4[2048];          // 32 KB: KH | KL | VH | VL
    char* sb = (char*)smem4;

    bhalf8 Qf[2][2][2];
#pragma unroll
    for (int nt = 0; nt < 2; ++nt)
#pragma unroll
        for (int dt = 0; dt < 2; ++dt) {
            const size_t o = (size_t)(q0 + 16 * nt + ln) * DHEAD + dt * 32 + 8 * h;
            Qf[nt][dt][0] = *reinterpret_cast<const bhalf8*>(qhp + o);
            Qf[nt][dt][1] = *reinterpret_cast<const bhalf8*>(qlp + o);
        }

    f32x4 accO[2][4];
#pragma unroll
    for (int a = 0; a < 2; ++a)
#pragma unroll
        for (int b = 0; b < 4; ++b) accO[a][b] = (f32x4){0.f, 0.f, 0.f, 0.f};
    float m_i[2] = {0.f, 0.f};
    float l_i[2] = {1.f, 1.f};
    const float scale = 0.125f;

    for (int kt16 = 0; kt16 < 16; ++kt16) {
        const int k0 = kt16 * 64;
        {
            const int r = tid >> 2, c = tid & 3;
            const int swz = (r & 7) << 4;
            const size_t gK = (size_t)(k0 + r) * DHEAD + c * 16;
            const size_t gV = (size_t)r * SEQ + k0 + c * 16;
            const int d0 = r * 128 + ((c * 32) ^ swz);
            const int d1 = r * 128 + ((c * 32 + 16) ^ swz);
            uint4 t;
            t = *reinterpret_cast<const uint4*>(khp + gK);
            *reinterpret_cast<uint4*>(sb + d0) = t;
            t = *reinterpret_cast<const uint4*>(khp + gK + 8);
            *reinterpret_cast<uint4*>(sb + d1) = t;
            t = *reinterpret_cast<const uint4*>(klp + gK);
            *reinterpret_cast<uint4*>(sb + 8192 + d0) = t;
            t = *reinterpret_cast<const uint4*>(klp + gK + 8);
            *reinterpret_cast<uint4*>(sb + 8192 + d1) = t;
            t = *reinterpret_cast<const uint4*>(vhp + gV);
            *reinterpret_cast<uint4*>(sb + 16384 + d0) = t;
            t = *reinterpret_cast<const uint4*>(vhp + gV + 8);
            *reinterpret_cast<uint4*>(sb + 16384 + d1) = t;
            t = *reinterpret_cast<const uint4*>(vlp + gV);
            *reinterpret_cast<uint4*>(sb + 24576 + d0) = t;
            t = *reinterpret_cast<const uint4*>(vlp + gV + 8);
            *reinterpret_cast<uint4*>(sb + 24576 + d1) = t;
        }
        __syncthreads();

        f32x4 s_[2][4];
#pragma unroll
        for (int a = 0; a < 2; ++a)
#pragma unroll
            for (int b = 0; b < 4; ++b) s_[a][b] = (f32x4){0.f, 0.f, 0.f, 0.f};
#pragma unroll
        for (int mt = 0; mt < 4; ++mt) {
            const int rr = 16 * mt + ln;
            const int sw = (rr & 7) << 4;
            const bhalf8 Ah0 = *reinterpret_cast<const bhalf8*>(sb + rr * 128 + ((16 * h) ^ sw));
            const bhalf8 Ah1 = *reinterpret_cast<const bhalf8*>(sb + rr * 128 + ((64 + 16 * h) ^ sw));
            const bhalf8 Al0 = *reinterpret_cast<const bhalf8*>(sb + 8192 + rr * 128 + ((16 * h) ^ sw));
            const bhalf8 Al1 = *reinterpret_cast<const bhalf8*>(sb + 8192 + rr * 128 + ((64 + 16 * h) ^ sw));
#pragma unroll
            for (int nt = 0; nt < 2; ++nt) {
                s_[nt][mt] = MFMA16(Ah0, Qf[nt][0][0], s_[nt][mt], 0, 0, 0);
                s_[nt][mt] = MFMA16(Ah1, Qf[nt][1][0], s_[nt][mt], 0, 0, 0);
                s_[nt][mt] = MFMA16(Ah0, Qf[nt][0][1], s_[nt][mt], 0, 0, 0);
                s_[nt][mt] = MFMA16(Ah1, Qf[nt][1][1], s_[nt][mt], 0, 0, 0);
                s_[nt][mt] = MFMA16(Al0, Qf[nt][0][0], s_[nt][mt], 0, 0, 0);
                s_[nt][mt] = MFMA16(Al1, Qf[nt][1][0], s_[nt][mt], 0, 0, 0);
            }
        }

        float Pv[2][4][4];
        bhalf8 Pfh[2][2], Pfl[2][2];
#pragma unroll
        for (int nt = 0; nt < 2; ++nt) {
            float mloc = -1e30f;
#pragma unroll
            for (int mt = 0; mt < 4; ++mt)
#pragma unroll
                for (int r = 0; r < 4; ++r) {
                    const float v = s_[nt][mt][r] * scale;
                    Pv[nt][mt][r] = v;
                    mloc = fmaxf(mloc, v);
                }
            mloc = fmaxf(mloc, __shfl_xor(mloc, 16));
            mloc = fmaxf(mloc, __shfl_xor(mloc, 32));
            const float mn = fmaxf(m_i[nt], mloc);
            const float sf = __expf(m_i[nt] - mn);
            m_i[nt] = mn;
            float rs = 0.f;
#pragma unroll
            for (int mt = 0; mt < 4; ++mt)
#pragma unroll
                for (int r = 0; r < 4; ++r) {
                    const float p = __expf(Pv[nt][mt][r] - mn);
                    Pv[nt][mt][r] = p;
                    rs += p;
                }
            rs += __shfl_xor(rs, 16);
            rs += __shfl_xor(rs, 32);
            l_i[nt] = l_i[nt] * sf + rs;
#pragma unroll
            for (int r = 0; r < 4; ++r) {
                const float sf_b = __shfl(sf, 20 * h + r);
#pragma unroll
                for (int ntd = 0; ntd < 4; ++ntd) accO[nt][ntd][r] *= sf_b;
            }
#pragma unroll
            for (int kt = 0; kt < 2; ++kt) {
                bhalf8 fh, fl;
#pragma unroll
                for (int j = 0; j < 8; ++j) {
                    const float p = Pv[nt][2 * kt + (j >> 2)][j & 3];
                    const unsigned short hi = f2bf(p);
                    fh[j] = (short)hi;
                    fl[j] = (short)f2bf(p - bf2f(hi));
                }
                Pfh[nt][kt] = fh;
                Pfl[nt][kt] = fl;
            }
        }

#pragma unroll
        for (int kt = 0; kt < 2; ++kt) {
#pragma unroll
            for (int ntd = 0; ntd < 4; ++ntd) {
                const int rr = 16 * ntd + ln;
                const int sw = (rr & 7) << 4;
                const int c0 = (64 * kt + 8 * h) ^ sw;
                const int c1 = (64 * kt + 32 + 8 * h) ^ sw;
                union { short4v q[2]; bhalf8 v; } ubh, ubl;
                ubh.q[0] = *reinterpret_cast<const short4v*>(sb + 16384 + rr * 128 + c0);
                ubh.q[1] = *reinterpret_cast<const short4v*>(sb + 16384 + rr * 128 + c1);
                ubl.q[0] = *reinterpret_cast<const short4v*>(sb + 24576 + rr * 128 + c0);
                ubl.q[1] = *reinterpret_cast<const short4v*>(sb + 24576 + rr * 128 + c1);
                const bhalf8 Bh = ubh.v;
                const bhalf8 Bl = ubl.v;
#pragma unroll
                for (int nt = 0; nt < 2; ++nt) {
                    accO[nt][ntd] = MFMA16(Pfh[nt][kt], Bh, accO[nt][ntd], 0, 0, 0);
                    accO[nt][ntd] = MFMA16(Pfh[nt][kt], Bl, accO[nt][ntd], 0, 0, 0);
                    accO[nt][ntd] = MFMA16(Pfl[nt][kt], Bh, accO[nt][ntd], 0, 0, 0);
                }
            }
        }
        __syncthreads();
    }

    const int bB = bh >> 4;
    const int hd = bh & 15;
#pragma unroll
    for (int nt = 0; nt < 2; ++nt) {
        float linv[4];
#pragma unroll
        for (int r = 0; r < 4; ++r) linv[r] = 1.0f / __shfl(l_i[nt], 20 * h + r);
#pragma unroll
        for (int r = 0; r < 4; ++r) {
            const int q = q0 + 16 * nt + 4 * h + r;
            float* orow = out + ((size_t)bB * SEQ + q) * C_OUT + hd * DHEAD + ln;
#pragma unroll
            for (int ntd = 0; ntd < 4; ++ntd)
                orow[16 * ntd] = accO[nt][ntd][r] * linv[r];
        }
    }
}

extern "C" void kernel_launch(void* const* d_in, const int* in_sizes, int n_in,
                              void* d_out, int out_size, void* d_ws, size_t ws_size,
                              hipStream_t stream) {
    const float* query = (const float*)d_in[0];
    const float* key   = (const float*)d_in[1];
    const float* value = (const float*)d_in[2];
    const float* wq    = (const float*)d_in[3];
    const float* bq    = (const float*)d_in[4];
    const float* wk    = (const float*)d_in[5];
    const float* bk    = (const float*)d_in[6];
    const float* wv    = (const float*)d_in[7];
    const float* bv    = (const float*)d_in[8];

    const size_t N = (size_t)NBH * SEQ * DHEAD;      // 4,194,304 elems
    const size_t W = (size_t)GROUPS * DPG * DPG;     // 262,144 elems
    unsigned short* qhb = (unsigned short*)d_ws;
    unsigned short* qlb = qhb + N;
    unsigned short* khb = qhb + 2 * N;
    unsigned short* klb = qhb + 3 * N;
    unsigned short* vhb = qhb + 4 * N;
    unsigned short* vlb = qhb + 5 * N;
    unsigned short* wqh = qhb + 6 * N;
    unsigned short* wql = wqh + W;
    unsigned short* wkh = wqh + 2 * W;
    unsigned short* wkl = wqh + 3 * W;
    unsigned short* wvh = wqh + 4 * W;
    unsigned short* wvl = wqh + 5 * W;               // ~51.5 MB total

    dim3 blk(256);
    dim3 wg(4, 4, 4);
    wsplit<<<wg, blk, 0, stream>>>(wq, wqh, wql);
    wsplit<<<wg, blk, 0, stream>>>(wk, wkh, wkl);
    wsplit<<<wg, blk, 0, stream>>>(wv, wvh, wvl);

    dim3 pg(MROWS / 64, 2, GROUPS);                  // (64, 2, 4)
    proj_mfma<0><<<pg, blk, 0, stream>>>(query, wqh, wql, bq, qhb, qlb);
    proj_mfma<0><<<pg, blk, 0, stream>>>(key,   wkh, wkl, bk, khb, klb);
    proj_mfma<1><<<pg, blk, 0, stream>>>(value, wvh, wvl, bv, vhb, vlb);

    dim3 ag(SEQ / 128, NBH);                         // (8, 64)
    attn_mfma<<<ag, blk, 0, stream>>>(qhb, qlb, khb, klb, vhb, vlb, (float*)d_out);
}